// Round 8
// baseline (554.062 us; speedup 1.0000x reference)
//
#include <hip/hip_runtime.h>

#define GAMMA 0.1f
#define MIN_R 0.1f
#define THR 256

// ---------------- LJ force ---------------------------------------------------
__device__ __forceinline__ void lj_force(float dx, float dy, float dz,
                                         float& fx, float& fy, float& fz)
{
    float r2 = dx * dx + dy * dy + dz * dz;
    float rr = sqrtf(r2);
    float inv_norm = 1.0f / fmaxf(rr, 1e-12f);
    float rc = fmaxf(rr, MIN_R);
    float s1 = 1.0f / rc;                 // RC = 1
    float s2 = s1 * s1;
    float s6 = s2 * s2 * s2;
    float F = 4.0f * s6 * (12.0f * s6 - 6.0f) * s1;
    float sc = F * inv_norm;
    fx = sc * dx; fy = sc * dy; fz = sc * dz;
}

// ---------------- k0: out = -gamma * v ---------------------------------------
__global__ __launch_bounds__(THR) void init_out_kernel(
    const float* __restrict__ v, float* __restrict__ out, int n)
{
    int g = (blockIdx.x * THR + threadIdx.x) * 4;
    if (g + 3 < n) {
        float4 vg = *(const float4*)(v + g);
        float4 o;
        o.x = -GAMMA * vg.x;
        o.y = -GAMMA * vg.y;
        o.z = -GAMMA * vg.z;
        o.w = -GAMMA * vg.w;
        *(float4*)(out + g) = o;
    } else {
        for (; g < n; ++g) out[g] = -GAMMA * v[g];
    }
}

// ---------------- k1: per-edge force, fire-and-forget atomics ----------------
__global__ __launch_bounds__(THR) void edge_atomic_kernel(
    const float* __restrict__ x, const int* __restrict__ src,
    const int* __restrict__ dst, float* __restrict__ out, int n_edges)
{
    const int i4 = (blockIdx.x * THR + threadIdx.x) * 4;
    if (i4 + 3 < n_edges) {
        const int4 s4 = *(const int4*)(src + i4);
        const int4 d4 = *(const int4*)(dst + i4);
        const int sI[4] = {s4.x, s4.y, s4.z, s4.w};
        const int dI[4] = {d4.x, d4.y, d4.z, d4.w};
        float xs[4][3], xd[4][3];
        // issue all 24 gathers before any compute (MLP)
        #pragma unroll
        for (int k = 0; k < 4; ++k) {
            const int s3 = 3 * sI[k], d3 = 3 * dI[k];
            xs[k][0] = x[s3 + 0]; xs[k][1] = x[s3 + 1]; xs[k][2] = x[s3 + 2];
            xd[k][0] = x[d3 + 0]; xd[k][1] = x[d3 + 1]; xd[k][2] = x[d3 + 2];
        }
        #pragma unroll
        for (int k = 0; k < 4; ++k) {
            float fx, fy, fz;
            lj_force(xd[k][0] - xs[k][0], xd[k][1] - xs[k][1],
                     xd[k][2] - xs[k][2], fx, fy, fz);
            const int d3 = 3 * dI[k];
            unsafeAtomicAdd(&out[d3 + 0], fx);
            unsafeAtomicAdd(&out[d3 + 1], fy);
            unsafeAtomicAdd(&out[d3 + 2], fz);
        }
    } else {
        for (int e = i4; e < n_edges; ++e) {
            const int s3 = 3 * src[e], d3 = 3 * dst[e];
            float fx, fy, fz;
            lj_force(x[d3 + 0] - x[s3 + 0], x[d3 + 1] - x[s3 + 1],
                     x[d3 + 2] - x[s3 + 2], fx, fy, fz);
            unsafeAtomicAdd(&out[d3 + 0], fx);
            unsafeAtomicAdd(&out[d3 + 1], fy);
            unsafeAtomicAdd(&out[d3 + 2], fz);
        }
    }
}

extern "C" void kernel_launch(void* const* d_in, const int* in_sizes, int n_in,
                              void* d_out, int out_size, void* d_ws, size_t ws_size,
                              hipStream_t stream) {
    const float* x   = (const float*)d_in[0];
    const float* v   = (const float*)d_in[1];
    const int*   src = (const int*)d_in[2];
    const int*   dst = (const int*)d_in[3];
    float* out = (float*)d_out;

    const int n_out = out_size;
    const int n_edges = in_sizes[2];
    (void)d_ws; (void)ws_size;

    const int gi = ((n_out + 3) / 4 + THR - 1) / THR;
    const int ge = ((n_edges + 3) / 4 + THR - 1) / THR;

    init_out_kernel<<<gi, THR, 0, stream>>>(v, out, n_out);
    edge_atomic_kernel<<<ge, THR, 0, stream>>>(x, src, dst, out, n_edges);
}